// Round 5
// baseline (105.796 us; speedup 1.0000x reference)
//
#include <hip/hip_runtime.h>

#define BATCH 131072

typedef float v2f __attribute__((ext_vector_type(2)));

// ws layout (floats):
//  [0..53]     A: 6 matrices 3x3 (decoder collapsed: recon_k = (l^T A_k l)/(l^T l))
//  [64..99]    enc RX coeffs: gate g=bb*6+w -> ws[64+2g]=cos(tx/2), ws[65+2g]=sin(tx/2)
//  [128..511]  enc diag per block bb: ws[128+128*bb+2r]=Re D_r, +1=Im D_r

__device__ __forceinline__ float fast_tanh(float v) {
    float e = __expf(2.0f * v);
    return 1.0f - 2.0f / (e + 1.0f);
}

template <int CTRL>
__device__ __forceinline__ float dppf(float v) {
    return __int_as_float(__builtin_amdgcn_update_dpp(
        0, __float_as_int(v), CTRL, 0xF, 0xF, true));
}
#define DPP_XOR1 0xB1  // quad_perm [1,0,3,2]
#define DPP_XOR2 0x4E  // quad_perm [2,3,0,1]

__device__ __forceinline__ v2f swap2(v2f v) { return __builtin_shufflevector(v, v, 1, 0); }

// ---------------------------------------------------------------------------
// prep (unchanged)
// ---------------------------------------------------------------------------
__global__ __launch_bounds__(256) void prep_kernel(const float* __restrict__ enc_w,
                                                   const float* __restrict__ dec_w,
                                                   float* __restrict__ ws) {
    __shared__ float gt[18][8];
    __shared__ float Sr[64][8];
    __shared__ float Si[64][8];
    const int t = threadIdx.x;

    if (t < 18) {
        float tx = dec_w[t * 3 + 0];
        float tz = dec_w[t * 3 + 1];
        float c = cosf(0.5f * tx), s = sinf(0.5f * tx);
        float ch = cosf(0.5f * tz), sh = sinf(0.5f * tz);
        gt[t][0] = c * ch;  gt[t][1] = -c * sh;
        gt[t][2] = -s * sh; gt[t][3] = -s * ch;
        gt[t][4] = s * sh;  gt[t][5] = -s * ch;
        gt[t][6] = c * ch;  gt[t][7] = c * sh;
    }

    const int cl = t & 7;
    const int pr = t >> 3;
    float* fSr = &Sr[0][0];
    float* fSi = &Si[0][0];
    for (int f = t; f < 512; f += 256) {
        int r = f >> 3, c = f & 7;
        fSr[f] = (r == c && c < 3) ? 1.0f : 0.0f;
        fSi[f] = 0.0f;
    }

    for (int bb = 0; bb < 3; ++bb) {
        for (int w = 0; w < 6; ++w) {
            __syncthreads();
            int g = bb * 6 + w;
            int p = 5 - w;
            float u00r = gt[g][0], u00i = gt[g][1], u01r = gt[g][2], u01i = gt[g][3];
            float u10r = gt[g][4], u10i = gt[g][5], u11r = gt[g][6], u11i = gt[g][7];
            int r0 = ((pr >> p) << (p + 1)) | (pr & ((1 << p) - 1));
            int r1 = r0 | (1 << p);
            float ar = Sr[r0][cl], ai = Si[r0][cl];
            float br = Sr[r1][cl], bi = Si[r1][cl];
            Sr[r0][cl] = u00r * ar - u00i * ai + u01r * br - u01i * bi;
            Si[r0][cl] = u00r * ai + u00i * ar + u01r * bi + u01i * br;
            Sr[r1][cl] = u10r * ar - u10i * ai + u11r * br - u11i * bi;
            Si[r1][cl] = u10r * ai + u10i * ar + u11r * bi + u11i * br;
        }
        __syncthreads();
        for (int f = t; f < 512; f += 256) {
            int r = f >> 3;
            if (__popc(r & (r >> 1)) & 1) {
                fSr[f] = -fSr[f];
                fSi[f] = -fSi[f];
            }
        }
    }
    __syncthreads();

    if (t < 54) {
        int k = t / 9, d = (t % 9) / 3, e = t % 3;
        float acc = 0.0f;
        for (int r = 0; r < 64; ++r) {
            float term = Sr[r][d] * Sr[r][e] + Si[r][d] * Si[r][e];
            acc += ((r >> (5 - k)) & 1) ? -term : term;
        }
        ws[t] = acc;
    }

    if (t < 18) {
        float tx = enc_w[t * 3 + 0];
        ws[64 + 2 * t] = cosf(0.5f * tx);
        ws[65 + 2 * t] = sinf(0.5f * tx);
    }

    if (t >= 64 && t < 256) {
        int idx = t - 64;
        int bb = idx >> 6, r = idx & 63;
        float phi = 0.0f;
        for (int k = 0; k < 6; ++k) {
            float tz = enc_w[(bb * 6 + k) * 3 + 1];
            phi += ((r >> (5 - k)) & 1) ? 0.5f * tz : -0.5f * tz;
        }
        float sgn = (__popc(r & (r >> 1)) & 1) ? -1.0f : 1.0f;
        ws[128 + bb * 128 + 2 * r] = sgn * cosf(phi);
        ws[129 + bb * 128 + 2 * r] = sgn * sinf(phi);
    }
}

// ---------------------------------------------------------------------------
// Packed butterflies on TWO interleaved elements (e = 0,1).
// State: zr[e][j], pack j = (amp(m=2j), amp(m=2j+1)), amp r = 4m+sub.
// ---------------------------------------------------------------------------
template <int MASK>
__device__ __forceinline__ void rx_pairs2(v2f zr[2][8], v2f zi[2][8], float c, float s) {
#pragma unroll
    for (int j = 0; j < 8; ++j) {
        if (j & MASK) continue;
        int j1 = j | MASK;
#pragma unroll
        for (int e = 0; e < 2; ++e) {
            v2f ar = zr[e][j], ai = zi[e][j], br = zr[e][j1], bi = zi[e][j1];
            zr[e][j]  = c * ar + s * bi;
            zi[e][j]  = c * ai - s * br;
            zr[e][j1] = c * br + s * ai;
            zi[e][j1] = c * bi - s * ar;
        }
    }
}

template <int CTRL>
__device__ __forceinline__ void rx_exch22(v2f zr[2][8], v2f zi[2][8], float c, float s) {
#pragma unroll
    for (int j = 0; j < 8; ++j) {
#pragma unroll
        for (int e = 0; e < 2; ++e) {
            v2f pr, pi;
            pr.x = dppf<CTRL>(zr[e][j].x);
            pr.y = dppf<CTRL>(zr[e][j].y);
            pi.x = dppf<CTRL>(zi[e][j].x);
            pi.y = dppf<CTRL>(zi[e][j].y);
            v2f mr = zr[e][j], mi = zi[e][j];
            zr[e][j] = c * mr + s * pi;
            zi[e][j] = c * mi - s * pr;
        }
    }
}

// ---------------------------------------------------------------------------
// main: 4 threads per element, 2 elements per thread (ILP-2).
// Block covers 128 batch elements: el(e) = blockIdx*128 + 64*e + bl.
// sW layout as round 4: group g=j*4+su -> phys base g*16 + (g>>2)*4.
// ---------------------------------------------------------------------------
__global__ __launch_bounds__(256) void qae_main(const float* __restrict__ x,
                                                const float* __restrict__ Wp,
                                                const float* __restrict__ bp,
                                                const float* __restrict__ ws,
                                                float* __restrict__ out) {
    __shared__ float sW[540];
    __shared__ float sD[256];
    __shared__ float sLat[384];

    const int t = threadIdx.x;
    const int bl = t >> 2;
    const int sub = t & 3;

    for (int f = t; f < 512; f += 256) {
        int g = f >> 4, e = f & 15;
        int j = g >> 2, su = g & 3;
        float val;
        if (e < 12)      { int row = 8 * j + su + 4 * (e & 1); val = Wp[row * 6 + (e >> 1)]; }
        else if (e < 14) { int row = 8 * j + su + 4 * (e - 12); val = bp[row]; }
        else val = 0.0f;
        sW[g * 16 + j * 4 + e] = val;
    }
    if (t < 128) {
        int bb = t >> 6, r = t & 63;
        int su = r & 3, m = r >> 2, j = m >> 1, hm = m & 1;
        int base = ((bb * 8 + j) * 4 + su) * 4;
        sD[base + hm]     = ws[128 + bb * 128 + 2 * r];
        sD[base + 2 + hm] = ws[128 + bb * 128 + 2 * r + 1];
    }
    __syncthreads();

    const size_t b0 = (size_t)blockIdx.x * 128 + bl;       // element 0
    const size_t b1 = b0 + 64;                             // element 1
    float xv[2][6];
#pragma unroll
    for (int e = 0; e < 2; ++e) {
        const float* xp = x + (e ? b1 : b0) * 6;
        float2 a = *(const float2*)(xp);
        float2 bq = *(const float2*)(xp + 2);
        float2 c = *(const float2*)(xp + 4);
        xv[e][0] = a.x; xv[e][1] = a.y; xv[e][2] = bq.x;
        xv[e][3] = bq.y; xv[e][4] = c.x; xv[e][5] = c.y;
    }

    // h = tanh(xW^T+b) for both elements; shared W row reads
    v2f zr[2][8], zi[2][8];
    v2f S2[2] = {{0.0f, 0.0f}, {0.0f, 0.0f}};
#pragma unroll
    for (int j = 0; j < 8; ++j) {
        const float* wb = &sW[(j * 4 + sub) * 16 + j * 4];
        float4 c0 = *(const float4*)wb;
        float4 c1 = *(const float4*)(wb + 4);
        float4 c2 = *(const float4*)(wb + 8);
        float4 c3 = *(const float4*)(wb + 12);
#pragma unroll
        for (int e = 0; e < 2; ++e) {
            v2f a = {c3.x, c3.y};
            a += xv[e][0] * (v2f){c0.x, c0.y};
            a += xv[e][1] * (v2f){c0.z, c0.w};
            a += xv[e][2] * (v2f){c1.x, c1.y};
            a += xv[e][3] * (v2f){c1.z, c1.w};
            a += xv[e][4] * (v2f){c2.x, c2.y};
            a += xv[e][5] * (v2f){c2.z, c2.w};
            v2f th = {fast_tanh(a.x), fast_tanh(a.y)};
            zr[e][j] = th;
            zi[e][j] = (v2f){0.0f, 0.0f};
            S2[e] += th * th;
        }
    }
    float invS[2];
#pragma unroll
    for (int e = 0; e < 2; ++e) {
        float S = S2[e].x + S2[e].y;
        S += dppf<DPP_XOR1>(S);
        S += dppf<DPP_XOR2>(S);
        invS[e] = __builtin_amdgcn_rcpf(S);
    }

    // encoder circuit (last block's diagonal dropped: |D|=1)
#pragma unroll 1
    for (int bb = 0; bb < 3; ++bb) {
        const float* rx = ws + 64 + 12 * bb;   // uniform -> s_load
        rx_pairs2<4>(zr, zi, rx[0], rx[1]);
        rx_pairs2<2>(zr, zi, rx[2], rx[3]);
        rx_pairs2<1>(zr, zi, rx[4], rx[5]);
        {   // wire 3: within-pack swap
            float c = rx[6], s = rx[7];
#pragma unroll
            for (int j = 0; j < 8; ++j)
#pragma unroll
                for (int e = 0; e < 2; ++e) {
                    v2f orr = zr[e][j], oi = zi[e][j];
                    zr[e][j] = c * orr + s * swap2(oi);
                    zi[e][j] = c * oi - s * swap2(orr);
                }
        }
        rx_exch22<DPP_XOR2>(zr, zi, rx[8], rx[9]);    // wire 4
        rx_exch22<DPP_XOR1>(zr, zi, rx[10], rx[11]);  // wire 5
        if (bb < 2) {
#pragma unroll
            for (int j = 0; j < 8; ++j) {
                float4 d = *(const float4*)&sD[((bb * 8 + j) * 4 + sub) * 4];
                v2f dr = {d.x, d.y}, di = {d.z, d.w};
#pragma unroll
                for (int e = 0; e < 2; ++e) {
                    v2f orr = zr[e][j], oi = zi[e][j];
                    zr[e][j] = dr * orr - di * oi;
                    zi[e][j] = dr * oi + di * orr;
                }
            }
        }
    }

    // latent + decoder for both elements
    float rec[2][6];
    float lat[2][3];
#pragma unroll
    for (int e = 0; e < 2; ++e) {
        v2f L0 = {0, 0}, L1 = {0, 0}, L2 = {0, 0};
#pragma unroll
        for (int j = 0; j < 8; ++j) {
            v2f p = zr[e][j] * zr[e][j] + zi[e][j] * zi[e][j];
            L0 += (j & 4) ? -p : p;
            L1 += (j & 2) ? -p : p;
            L2 += (j & 1) ? -p : p;
        }
        float l0 = L0.x + L0.y, l1 = L1.x + L1.y, l2 = L2.x + L2.y;
        l0 += dppf<DPP_XOR1>(l0); l0 += dppf<DPP_XOR2>(l0);
        l1 += dppf<DPP_XOR1>(l1); l1 += dppf<DPP_XOR2>(l1);
        l2 += dppf<DPP_XOR1>(l2); l2 += dppf<DPP_XOR2>(l2);
        l0 *= invS[e]; l1 *= invS[e]; l2 *= invS[e];
        lat[e][0] = l0; lat[e][1] = l1; lat[e][2] = l2;

        float r2 = l0 * l0 + l1 * l1 + l2 * l2;
        float invr2 = __builtin_amdgcn_rcpf(r2);
        float lv[3] = {l0, l1, l2};
#pragma unroll
        for (int k = 0; k < 6; ++k) {
            float acc = 0.0f;
#pragma unroll
            for (int d = 0; d < 3; ++d)
#pragma unroll
                for (int e2 = 0; e2 < 3; ++e2) acc += ws[k * 9 + d * 3 + e2] * lv[d] * lv[e2];
            rec[e][k] = acc * invr2;
        }
    }

    // latent out (staged; block covers 128 elements -> 384 floats)
    if (sub == 0) {
#pragma unroll
        for (int e = 0; e < 2; ++e) {
            sLat[(64 * e + bl) * 3 + 0] = lat[e][0];
            sLat[(64 * e + bl) * 3 + 1] = lat[e][1];
            sLat[(64 * e + bl) * 3 + 2] = lat[e][2];
        }
    }
    __syncthreads();
    for (int f = t; f < 384; f += 256)
        out[(size_t)BATCH * 64 + (size_t)blockIdx.x * 384 + f] = sLat[f];

    // reconstructed = tanh(rec W^T + b); shared weight reads for both elements
#pragma unroll
    for (int jj = 0; jj < 2; ++jj) {
        int jrow = 2 * sub + jj;
        float vlo[2][4], vhi[2][4];
#pragma unroll
        for (int su2 = 0; su2 < 4; ++su2) {
            int g = jrow * 4 + su2;
            const float* wb = &sW[g * 16 + jrow * 4];
            float4 c0 = *(const float4*)wb;
            float4 c1 = *(const float4*)(wb + 4);
            float4 c2 = *(const float4*)(wb + 8);
            float2 b2 = *(const float2*)(wb + 12);
#pragma unroll
            for (int e = 0; e < 2; ++e) {
                v2f a = {b2.x, b2.y};
                a += rec[e][0] * (v2f){c0.x, c0.y};
                a += rec[e][1] * (v2f){c0.z, c0.w};
                a += rec[e][2] * (v2f){c1.x, c1.y};
                a += rec[e][3] * (v2f){c1.z, c1.w};
                a += rec[e][4] * (v2f){c2.x, c2.y};
                a += rec[e][5] * (v2f){c2.z, c2.w};
                vlo[e][su2] = fast_tanh(a.x);
                vhi[e][su2] = fast_tanh(a.y);
            }
        }
#pragma unroll
        for (int e = 0; e < 2; ++e) {
            const size_t ob = (e ? b1 : b0) * 64;
            float4 o0 = {vlo[e][0], vlo[e][1], vlo[e][2], vlo[e][3]};
            float4 o1 = {vhi[e][0], vhi[e][1], vhi[e][2], vhi[e][3]};
            *(float4*)&out[ob + 8 * jrow]     = o0;
            *(float4*)&out[ob + 8 * jrow + 4] = o1;
        }
    }
}

extern "C" void kernel_launch(void* const* d_in, const int* in_sizes, int n_in,
                              void* d_out, int out_size, void* d_ws, size_t ws_size,
                              hipStream_t stream) {
    const float* x   = (const float*)d_in[0];
    const float* Wp  = (const float*)d_in[1];
    const float* bpv = (const float*)d_in[2];
    const float* enc = (const float*)d_in[3];
    const float* dec = (const float*)d_in[4];
    float* out = (float*)d_out;
    float* ws  = (float*)d_ws;

    prep_kernel<<<1, 256, 0, stream>>>(enc, dec, ws);
    qae_main<<<BATCH / 128, 256, 0, stream>>>(x, Wp, bpv, ws, out);
}